// Round 13
// baseline (179.344 us; speedup 1.0000x reference)
//
#include <hip/hip_runtime.h>
#include <math.h>

#define D_DIM 4096
#define NWG 1280                      // 5 WGs/CU x 256 CUs
#define WAVES_PER_WG 2
#define WSTRIDE (NWG * WAVES_PER_WG)  // 2560 waves; ~6.4 rows/wave

typedef float v2f __attribute__((ext_vector_type(2)));

// ---- packed-f32 butterfly primitives (VOP3P) ----
__device__ __forceinline__ v2f bfly0(v2f a) {
    v2f d;
    asm("v_pk_add_f32 %0, %1, %2 op_sel:[0,1] op_sel_hi:[0,1] neg_hi:[0,1]"
        : "=v"(d) : "v"(a), "v"(a));
    return d;
}
__device__ __forceinline__ v2f pkadd(v2f a, v2f b) {
    v2f d; asm("v_pk_add_f32 %0, %1, %2" : "=v"(d) : "v"(a), "v"(b)); return d;
}
__device__ __forceinline__ v2f pksub(v2f a, v2f b) {
    v2f d; asm("v_pk_add_f32 %0, %1, %2 neg_lo:[0,1] neg_hi:[0,1]" : "=v"(d) : "v"(a), "v"(b)); return d;
}
__device__ __forceinline__ v2f pkmul(v2f a, v2f b) {
    v2f d; asm("v_pk_mul_f32 %0, %1, %2" : "=v"(d) : "v"(a), "v"(b)); return d;
}

// In-register FWHT over 6 bits: 64 values as 32 packed v2f (verified r2-r12).
__device__ __forceinline__ void radix64(v2f w[32]) {
#pragma unroll
    for (int p = 0; p < 32; ++p) w[p] = bfly0(w[p]);
#pragma unroll
    for (int s = 0; s < 5; ++s) {
        const int d = 1 << s;
#pragma unroll
        for (int p = 0; p < 32; ++p) {
            if (!(p & d)) {
                const v2f a = w[p];
                const v2f b = w[p + d];
                w[p]     = pkadd(a, b);
                w[p + d] = pksub(a, b);
            }
        }
    }
}

// async global->LDS, 16 B per lane; LDS dest = wave-uniform base + lane*16.
__device__ __forceinline__ void gload_lds16(const float* g, float* lp) {
    __builtin_amdgcn_global_load_lds(
        (const __attribute__((address_space(1))) void*)g,
        (__attribute__((address_space(3))) void*)lp, 16, 0, 0);
}

// All trb accesses as inline asm: invisible to LDS-DMA alias analysis, so the
// compiler cannot insert conservative vmcnt drains (R4/R11 lesson). Intra-wave
// DS ops execute in order -> write->read hazards need no barrier; only
// lgkmcnt(0)+sched_barrier before consuming read results (rule 18).
__device__ __forceinline__ float4 ds_read128(unsigned byte_addr) {
    float4 d;
    asm volatile("ds_read_b128 %0, %1" : "=v"(d) : "v"(byte_addr));
    return d;
}
__device__ __forceinline__ void ds_write32(unsigned byte_addr, float val) {
    asm volatile("ds_write_b32 %0, %1" : : "v"(byte_addr), "v"(val));
}
__device__ __forceinline__ void wait_lgkm0() {
    asm volatile("s_waitcnt lgkmcnt(0)" ::: "memory");
    __builtin_amdgcn_sched_barrier(0);
}

// u_perm[l*64 + m] = u[e]/64, e = (l>>2)*256 + m*4 + (l&3)  (B-layout).
__global__ void compute_u_kernel(const float* __restrict__ g_mu,
                                 const float* __restrict__ g_rho,
                                 const float* __restrict__ eps,
                                 float* __restrict__ u_perm) {
    const int j = blockIdx.x * blockDim.x + threadIdx.x;
    if (j < D_DIM) {
        const int e = ((j >> 8) << 8) | ((j & 63) << 2) | ((j >> 6) & 3);
        const float r = g_rho[e];
        const float sp = (r > 20.0f) ? r : log1pf(expf(r));
        u_perm[j] = (g_mu[e] + sp * eps[e]) * 0.015625f;
    }
}

// Persistent wave-local kernel. 1280 WGs x 2 waves; each wave owns a 16 KB
// trb slice, processes rows wid, wid+2560, ... with ZERO barriers.
// trb double-duty: glds destination (linear x stage) at row top, transpose
// buffer mid-row; next-row glds issued right after T2 reads retire.
// vmcnt algebra (in-order retirement), steady state:
//   top: outstanding = glds_r(16,oldest) + stores_{r-1}(16); vmcnt(16)
//        retires exactly glds_r.  S1 issued BEFORE glds_{r+1} -> its
//        compiler wait = vmcnt(16), keeps the prefetch in flight.
__global__ __launch_bounds__(128, 2) void whvi_kernel(const float* __restrict__ x,
                                                      const float* __restrict__ s1,
                                                      const float* __restrict__ s2,
                                                      const float* __restrict__ u_perm,
                                                      float* __restrict__ out,
                                                      int nrows) {
    __shared__ float trb_all[WAVES_PER_WG * D_DIM];  // 32 KB: 16 KB per wave
    const int l = threadIdx.x & 63;
    const int wv = threadIdx.x >> 6;
    float* __restrict__ trb = &trb_all[wv << 12];
    const unsigned tb = (unsigned)(uintptr_t)trb;
    const int l4 = l << 2;
    const int L4 = (l & 15) << 2;

    const int wid = blockIdx.x * WAVES_PER_WG + wv;
    if (wid >= nrows) return;  // no barriers -> safe early exit

    // ---- prologue: glds row wid into trb, drain ----
    {
        const float* xr = x + (size_t)wid * D_DIM;
#pragma unroll
        for (int k = 0; k < 16; ++k) gload_lds16(xr + (k << 8) + l4, trb + (k << 8));
    }
    asm volatile("s_waitcnt vmcnt(0)" ::: "memory");
    __builtin_amdgcn_sched_barrier(0);

    for (int row = wid; row < nrows; row += WSTRIDE) {
        // ---- top: retire this row's glds, keep prev stores in flight ----
        asm volatile("s_waitcnt vmcnt(16)" ::: "memory");
        __builtin_amdgcn_sched_barrier(0);

        v2f w[32];

        // ---- phase A: x from trb (linear b128) * s2, FWHT bits {0,1,8..11} ----
        // two batches of 8 to cap register pressure
#pragma unroll
        for (int h = 0; h < 2; ++h) {
            float4 S2v[8];
#pragma unroll
            for (int k = 0; k < 8; ++k)
                S2v[k] = *reinterpret_cast<const float4*>(s2 + ((h * 8 + k) << 8) + l4);
            float4 X[8];
#pragma unroll
            for (int k = 0; k < 8; ++k)
                X[k] = ds_read128(tb + (unsigned)(((h * 8 + k) << 10) + (l << 4)));
            wait_lgkm0();
#pragma unroll
            for (int k = 0; k < 8; ++k) {
                const int p = 2 * (h * 8 + k);
                w[p]     = pkmul((v2f){X[k].x, X[k].y}, (v2f){S2v[k].x, S2v[k].y});
                w[p + 1] = pkmul((v2f){X[k].z, X[k].w}, (v2f){S2v[k].z, S2v[k].w});
            }
        }
        radix64(w);

        // ---- T1: scatter b32 writes, swizzled b128 reads (verified r3/r12) ----
#pragma unroll
        for (int v = 0; v < 64; ++v) {
            const unsigned a = tb + (unsigned)((((v << 6) + (l ^ ((v & 15) << 2))) << 2));
            ds_write32(a, (v & 1) ? w[v >> 1].y : w[v >> 1].x);
        }
        {
            // U loads issued here (L2-hot); consumed after the next radix64
            float4 Uv[16];
#pragma unroll
            for (int k = 0; k < 16; ++k)
                Uv[k] = *reinterpret_cast<const float4*>(u_perm + (l << 6) + (k << 2));
            float4 F[16];
#pragma unroll
            for (int k = 0; k < 16; ++k)
                F[k] = ds_read128(tb + (unsigned)(((l << 6) + ((k << 2) ^ L4)) << 2));
            wait_lgkm0();
#pragma unroll
            for (int k = 0; k < 16; ++k) {
                w[2 * k]     = (v2f){F[k].x, F[k].y};
                w[2 * k + 1] = (v2f){F[k].z, F[k].w};
            }
            // ---- phase B: FWHT bits {2..7}, *u, FWHT bits {2..7} ----
            radix64(w);
#pragma unroll
            for (int k = 0; k < 16; ++k) {
                w[2 * k]     = pkmul(w[2 * k],     (v2f){Uv[k].x, Uv[k].y});
                w[2 * k + 1] = pkmul(w[2 * k + 1], (v2f){Uv[k].z, Uv[k].w});
            }
            radix64(w);
        }

        // ---- S1 loads: BEFORE glds so their wait keeps the prefetch alive ----
        float4 S1v[16];
#pragma unroll
        for (int k = 0; k < 16; ++k)
            S1v[k] = *reinterpret_cast<const float4*>(s1 + (k << 8) + l4);
        __builtin_amdgcn_sched_barrier(0);

        // ---- T2 ----
#pragma unroll
        for (int m = 0; m < 64; ++m) {
            const unsigned a = tb + (unsigned)((((m << 6) + (l ^ ((m & 15) << 2))) << 2));
            ds_write32(a, (m & 1) ? w[m >> 1].y : w[m >> 1].x);
        }
        float4 F2[16];
#pragma unroll
        for (int k = 0; k < 16; ++k)
            F2[k] = ds_read128(tb + (unsigned)(((l << 6) + ((k << 2) ^ L4)) << 2));
        wait_lgkm0();  // trb now dead for this row

        // ---- prefetch next row into trb (lands during tail + next top) ----
        {
            const int pr = min(row + WSTRIDE, nrows - 1);
            const float* xn = x + (size_t)pr * D_DIM;
#pragma unroll
            for (int k = 0; k < 16; ++k) gload_lds16(xn + (k << 8) + l4, trb + (k << 8));
        }
        __builtin_amdgcn_sched_barrier(0);

        // ---- phase A': FWHT bits {0,1,8..11}, *s1, coalesced b128 stores ----
#pragma unroll
        for (int k = 0; k < 16; ++k) {
            w[2 * k]     = (v2f){F2[k].x, F2[k].y};
            w[2 * k + 1] = (v2f){F2[k].z, F2[k].w};
        }
        radix64(w);
        float* __restrict__ orow = out + (size_t)row * D_DIM;
#pragma unroll
        for (int k = 0; k < 16; ++k) {
            const v2f o0 = pkmul(w[2 * k],     (v2f){S1v[k].x, S1v[k].y});
            const v2f o1 = pkmul(w[2 * k + 1], (v2f){S1v[k].z, S1v[k].w});
            *reinterpret_cast<float4*>(orow + (k << 8) + l4) =
                make_float4(o0.x, o0.y, o1.x, o1.y);
        }
    }
}

extern "C" void kernel_launch(void* const* d_in, const int* in_sizes, int n_in,
                              void* d_out, int out_size, void* d_ws, size_t ws_size,
                              hipStream_t stream) {
    const float* x     = (const float*)d_in[0];
    const float* s1    = (const float*)d_in[1];
    const float* s2    = (const float*)d_in[2];
    const float* g_mu  = (const float*)d_in[3];
    const float* g_rho = (const float*)d_in[4];
    const float* eps   = (const float*)d_in[5];
    // d_in[6] = H : realized implicitly by the FWHT butterflies.

    float* u_perm = (float*)d_ws;
    float* out    = (float*)d_out;

    const int N = in_sizes[0] / D_DIM;

    compute_u_kernel<<<(D_DIM + 255) / 256, 256, 0, stream>>>(g_mu, g_rho, eps, u_perm);
    whvi_kernel<<<NWG, 128, 0, stream>>>(x, s1, s2, u_perm, out, N);
}